// Round 1
// baseline (7234.004 us; speedup 1.0000x reference)
//
#include <hip/hip_runtime.h>
#include <math.h>

#define NB 8
#define NIN 16384
#define NP 2048
#define KNN 32
#define TOTPTS (NB * NP)   // 16384

#define NEG_INF (-__builtin_inff())

// ---------------------------------------------------------------------------
// FPS: one block per batch, 1024 threads, 16 points/thread in registers.
// Bit-exact vs reference: rn ops, ((dx2+dy2)+dz2), argmax first-index ties.
// ---------------------------------------------------------------------------
__global__ __launch_bounds__(1024) void fps_kernel(const float* __restrict__ x,
                                                   float* __restrict__ partial) {
  const int b = blockIdx.x;
  const int t = threadIdx.x;
  const float* xb = x + (size_t)b * NIN * 3;
  float* pb = partial + (size_t)b * NP * 3;
  float px[16], py[16], pz[16], dd[16];
#pragma unroll
  for (int j = 0; j < 16; ++j) {
    int i = j * 1024 + t;
    px[j] = xb[3 * i];
    py[j] = xb[3 * i + 1];
    pz[j] = xb[3 * i + 2];
  }
  float qx = xb[0], qy = xb[1], qz = xb[2];
  if (t == 0) { pb[0] = qx; pb[1] = qy; pb[2] = qz; }
#pragma unroll
  for (int j = 0; j < 16; ++j) {
    float dx = __fsub_rn(px[j], qx), dy = __fsub_rn(py[j], qy), dz = __fsub_rn(pz[j], qz);
    dd[j] = __fadd_rn(__fadd_rn(__fmul_rn(dx, dx), __fmul_rn(dy, dy)), __fmul_rn(dz, dz));
  }
  __shared__ float sv[16];
  __shared__ int si[16];
  __shared__ float spx, spy, spz;
  __shared__ int sbi;
  for (int it = 1; it < NP; ++it) {
    // thread-local argmax (ascending j -> first-max kept)
    float bv = dd[0];
    int bj = 0;
#pragma unroll
    for (int j = 1; j < 16; ++j) {
      if (dd[j] > bv) { bv = dd[j]; bj = j; }
    }
    int bi = bj * 1024 + t;
    // wave argmax, tie -> lower global index
#pragma unroll
    for (int off = 32; off; off >>= 1) {
      float ov = __shfl_xor(bv, off);
      int oi = __shfl_xor(bi, off);
      if (ov > bv || (ov == bv && oi < bi)) { bv = ov; bi = oi; }
    }
    if ((t & 63) == 0) { sv[t >> 6] = bv; si[t >> 6] = bi; }
    __syncthreads();
    if (t < 16) {
      bv = sv[t];
      bi = si[t];
#pragma unroll
      for (int off = 8; off; off >>= 1) {
        float ov = __shfl_xor(bv, off);
        int oi = __shfl_xor(bi, off);
        if (ov > bv || (ov == bv && oi < bi)) { bv = ov; bi = oi; }
      }
      if (t == 0) sbi = bi;
    }
    __syncthreads();
    const int gbi = sbi;
    if (t == (gbi & 1023)) {
      const int jj = gbi >> 10;
      float cx = px[0], cy = py[0], cz = pz[0];
#pragma unroll
      for (int j = 1; j < 16; ++j) {
        if (j == jj) { cx = px[j]; cy = py[j]; cz = pz[j]; }
      }
      spx = cx; spy = cy; spz = cz;
      pb[3 * it] = cx; pb[3 * it + 1] = cy; pb[3 * it + 2] = cz;
    }
    __syncthreads();
    qx = spx; qy = spy; qz = spz;
#pragma unroll
    for (int j = 0; j < 16; ++j) {
      float dx = __fsub_rn(px[j], qx), dy = __fsub_rn(py[j], qy), dz = __fsub_rn(pz[j], qz);
      float nd = __fadd_rn(__fadd_rn(__fmul_rn(dx, dx), __fmul_rn(dy, dy)), __fmul_rn(dz, dz));
      dd[j] = fminf(dd[j], nd);
    }
  }
}

// ---------------------------------------------------------------------------
// xx[i] = sum_c F[i][c]^2  (rn, ascending c)
// ---------------------------------------------------------------------------
__global__ void xx_kernel(const float* __restrict__ F, float* __restrict__ xxg, int C) {
  int i = blockIdx.x * 256 + threadIdx.x;
  if (i >= TOTPTS) return;
  const float* f = F + (size_t)i * C;
  float s = 0.f;
  for (int c = 0; c < C; ++c) s = __fadd_rn(s, __fmul_rn(f[c], f[c]));
  xxg[i] = s;
}

// ---------------------------------------------------------------------------
// D[n][m] = (2*<f_n,f_m> - xx[n]) - xx[m]   (neg squared dist), one batch.
// 64x64 tiles, 256 threads, 4x4 per thread.
// ---------------------------------------------------------------------------
template <int C>
__global__ __launch_bounds__(256) void dist_gemm(const float* __restrict__ F,
                                                 const float* __restrict__ xxg,
                                                 float* __restrict__ D, int b) {
  __shared__ float As[64][C + 1];
  __shared__ float Bs[64][C + 1];
  const int tid = threadIdx.x;
  const int n0 = blockIdx.y * 64, m0 = blockIdx.x * 64;
  const float* Fb = F + (size_t)b * NP * C;
  const float* xxb = xxg + b * NP;
  for (int t = tid; t < 64 * C; t += 256) {
    int r = t / C, c = t - r * C;
    As[r][c] = Fb[(size_t)(n0 + r) * C + c];
    Bs[r][c] = Fb[(size_t)(m0 + r) * C + c];
  }
  __syncthreads();
  const int tx = tid & 15, ty = tid >> 4;
  float acc[4][4] = {};
  for (int c = 0; c < C; ++c) {
    float a[4], bb[4];
#pragma unroll
    for (int i = 0; i < 4; ++i) a[i] = As[ty * 4 + i][c];
#pragma unroll
    for (int j = 0; j < 4; ++j) bb[j] = Bs[tx * 4 + j][c];
#pragma unroll
    for (int i = 0; i < 4; ++i)
#pragma unroll
      for (int j = 0; j < 4; ++j) acc[i][j] = fmaf(a[i], bb[j], acc[i][j]);
  }
#pragma unroll
  for (int i = 0; i < 4; ++i) {
    int n = n0 + ty * 4 + i;
    float xn = xxb[n];
    float4 o;
    o.x = __fsub_rn(__fsub_rn(2.0f * acc[i][0], xn), xxb[m0 + tx * 4 + 0]);
    o.y = __fsub_rn(__fsub_rn(2.0f * acc[i][1], xn), xxb[m0 + tx * 4 + 1]);
    o.z = __fsub_rn(__fsub_rn(2.0f * acc[i][2], xn), xxb[m0 + tx * 4 + 2]);
    o.w = __fsub_rn(__fsub_rn(2.0f * acc[i][3], xn), xxb[m0 + tx * 4 + 3]);
    *(float4*)&D[(size_t)n * NP + m0 + tx * 4] = o;
  }
}

// ---------------------------------------------------------------------------
// top-32 (by value, ties -> lower index) per row; one wave per row.
// ---------------------------------------------------------------------------
__global__ __launch_bounds__(256) void select_kernel(const float* __restrict__ D,
                                                     int* __restrict__ idxg, int b) {
  const int lane = threadIdx.x & 63;
  const int row = blockIdx.x * 4 + (threadIdx.x >> 6);
  const float* Drow = D + (size_t)row * NP;
  float v[32];
#pragma unroll
  for (int s = 0; s < 32; ++s) v[s] = Drow[s * 64 + lane];
  int* out = idxg + ((size_t)b * NP + row) * KNN;
  for (int t = 0; t < KNN; ++t) {
    float bv = v[0];
    int bs = 0;
#pragma unroll
    for (int s = 1; s < 32; ++s) {
      if (v[s] > bv) { bv = v[s]; bs = s; }
    }
    int bi = bs * 64 + lane;
#pragma unroll
    for (int off = 32; off; off >>= 1) {
      float ov = __shfl_xor(bv, off);
      int oi = __shfl_xor(bi, off);
      if (ov > bv || (ov == bv && oi < bi)) { bv = ov; bi = oi; }
    }
    if (lane == 0) out[t] = bi;
    const bool own = (lane == (bi & 63));
    const int cs = bi >> 6;
#pragma unroll
    for (int s = 0; s < 32; ++s)
      if (own && s == cs) v[s] = NEG_INF;
  }
}

// ---------------------------------------------------------------------------
// Per-point projections: Uq = Wq1*x, Uqc = (Wq2-Wq1)*x + bq (same for K),
// Uv = Wv1*x, W6 = (Wv2-Wv1)*x + bv + (Wp*pos + bp).
// ---------------------------------------------------------------------------
template <int C, int DIM>
__global__ __launch_bounds__(256) void proj_kernel(
    const float* __restrict__ F, const float* __restrict__ pos,
    const float* __restrict__ Wq, const float* __restrict__ bq,
    const float* __restrict__ Wk, const float* __restrict__ bk,
    const float* __restrict__ Wv, const float* __restrict__ bv,
    const float* __restrict__ Wp, const float* __restrict__ bp,
    float* __restrict__ Uq, float* __restrict__ Uk, float* __restrict__ Uv,
    float* __restrict__ Uqc, float* __restrict__ Ukc, float* __restrict__ W6) {
  constexpr int PTS = 16;
  constexpr int GROUPS = 256 / DIM;
  constexpr int PPT = PTS / GROUPS;
  __shared__ float xs[PTS][C];
  __shared__ float ps[PTS][3];
  const int tid = threadIdx.x;
  const int base = blockIdx.x * PTS;
  for (int t = tid; t < PTS * C; t += 256) {
    int r = t / C;
    xs[r][t - r * C] = F[(size_t)(base + r) * C + (t - r * C)];
  }
  for (int t = tid; t < PTS * 3; t += 256) {
    int r = t / 3;
    ps[r][t - r * 3] = pos[(size_t)(base + r) * 3 + (t - r * 3)];
  }
  __syncthreads();
  const int g = tid / DIM;
  const int d = tid - g * DIM;
  float uq[PPT], uqd[PPT], uk[PPT], ukd[PPT], uv[PPT], uvd[PPT];
#pragma unroll
  for (int p = 0; p < PPT; ++p) { uq[p] = uqd[p] = uk[p] = ukd[p] = uv[p] = uvd[p] = 0.f; }
  const float* wqr = Wq + (size_t)d * (2 * C);
  const float* wkr = Wk + (size_t)d * (2 * C);
  const float* wvr = Wv + (size_t)d * (2 * C);
  for (int c = 0; c < C; ++c) {
    const float wq1 = wqr[c], wqd_ = wqr[C + c] - wq1;
    const float wk1 = wkr[c], wkd_ = wkr[C + c] - wk1;
    const float wv1 = wvr[c], wvd_ = wvr[C + c] - wv1;
#pragma unroll
    for (int p = 0; p < PPT; ++p) {
      const float xc = xs[g + p * GROUPS][c];
      uq[p] = fmaf(wq1, xc, uq[p]);
      uqd[p] = fmaf(wqd_, xc, uqd[p]);
      uk[p] = fmaf(wk1, xc, uk[p]);
      ukd[p] = fmaf(wkd_, xc, ukd[p]);
      uv[p] = fmaf(wv1, xc, uv[p]);
      uvd[p] = fmaf(wvd_, xc, uvd[p]);
    }
  }
  const float bqd = bq[d], bkd = bk[d], bvd = bv[d];
  const float wp0 = Wp[d * 3], wp1 = Wp[d * 3 + 1], wp2 = Wp[d * 3 + 2], bpd = bp[d];
#pragma unroll
  for (int p = 0; p < PPT; ++p) {
    const int lp = g + p * GROUPS;
    const size_t o = (size_t)(base + lp) * DIM + d;
    const float pd = wp0 * ps[lp][0] + wp1 * ps[lp][1] + wp2 * ps[lp][2] + bpd;
    Uq[o] = uq[p];
    Uqc[o] = uqd[p] + bqd;
    Uk[o] = uk[p];
    Ukc[o] = ukd[p] + bkd;
    Uv[o] = uv[p];
    W6[o] = uvd[p] + bvd + pd;
  }
}

// ---------------------------------------------------------------------------
// Attention: per point, logits_k = <Uq[ik]+Uqc[n], Uk[ik]+Ukc[n]>/sqrt(DIM),
// softmax over k, out_d = sum_k attn_k * (Uv[ik][d] + W6[n][d]).
// One wave per point, 4 points per block.
// ---------------------------------------------------------------------------
template <int DIM>
__global__ __launch_bounds__(256) void attn_kernel(
    const float* __restrict__ Uq, const float* __restrict__ Uk, const float* __restrict__ Uv,
    const float* __restrict__ Uqc, const float* __restrict__ Ukc, const float* __restrict__ W6g,
    const int* __restrict__ idxg, float* __restrict__ outF) {
  const int w = threadIdx.x >> 6, lane = threadIdx.x & 63;
  const int pt = blockIdx.x * 4 + w;
  const int b = pt >> 11;
  __shared__ int sidx[4][KNN];
  __shared__ float sqc[4][DIM], skc[4][DIM], sw6[4][DIM];
  __shared__ float sattn[4][KNN];
  const size_t rowo = (size_t)pt * DIM;
  if (lane < KNN) sidx[w][lane] = idxg[(size_t)pt * KNN + lane];
  for (int d = lane; d < DIM; d += 64) {
    sqc[w][d] = Uqc[rowo + d];
    skc[w][d] = Ukc[rowo + d];
    sw6[w][d] = W6g[rowo + d];
  }
  __syncthreads();
  if (lane < KNN) {
    const int ik = sidx[w][lane];
    const float* qr = Uq + (size_t)(b * NP + ik) * DIM;
    const float* kr = Uk + (size_t)(b * NP + ik) * DIM;
    float lg = 0.f;
    for (int d = 0; d < DIM; d += 4) {
      float4 qa = *(const float4*)(qr + d);
      float4 ka = *(const float4*)(kr + d);
      float4 qc = *(const float4*)(&sqc[w][d]);
      float4 kc = *(const float4*)(&skc[w][d]);
      lg += (qa.x + qc.x) * (ka.x + kc.x);
      lg += (qa.y + qc.y) * (ka.y + kc.y);
      lg += (qa.z + qc.z) * (ka.z + kc.z);
      lg += (qa.w + qc.w) * (ka.w + kc.w);
    }
    lg /= sqrtf((float)DIM);
    float m = lg;
#pragma unroll
    for (int off = 16; off; off >>= 1) m = fmaxf(m, __shfl_xor(m, off));
    float e = expf(lg - m);
    float s = e;
#pragma unroll
    for (int off = 16; off; off >>= 1) s += __shfl_xor(s, off);
    sattn[w][lane] = e / s;
  }
  __syncthreads();
  float acc[DIM / 64];
#pragma unroll
  for (int q = 0; q < DIM / 64; ++q) acc[q] = 0.f;
  for (int k = 0; k < KNN; ++k) {
    const int ik = sidx[w][k];
    const float a = sattn[w][k];
    const float* vr = Uv + (size_t)(b * NP + ik) * DIM;
#pragma unroll
    for (int q = 0; q < DIM / 64; ++q) {
      const int d = q * 64 + lane;
      acc[q] = fmaf(a, vr[d] + sw6[w][d], acc[q]);
    }
  }
#pragma unroll
  for (int q = 0; q < DIM / 64; ++q) outF[rowo + q * 64 + lane] = acc[q];
}

// ---------------------------------------------------------------------------
// Pooling: out[b][c] = max_n feats, out[b][256+c] = mean_n feats.
// feats channels: x1(0-63), x2(64-127), x3(128-255). One block per batch.
// ---------------------------------------------------------------------------
__global__ __launch_bounds__(256) void pool_kernel(const float* __restrict__ x1,
                                                   const float* __restrict__ x2,
                                                   const float* __restrict__ x3,
                                                   float* __restrict__ out) {
  const int b = blockIdx.x, c = threadIdx.x;
  const float* src;
  int dim, cl;
  if (c < 64) {
    src = x1 + (size_t)b * NP * 64; dim = 64; cl = c;
  } else if (c < 128) {
    src = x2 + (size_t)b * NP * 64; dim = 64; cl = c - 64;
  } else {
    src = x3 + (size_t)b * NP * 128; dim = 128; cl = c - 128;
  }
  float mx = NEG_INF, sm = 0.f;
#pragma unroll 8
  for (int n = 0; n < NP; ++n) {
    float v = src[(size_t)n * dim + cl];
    mx = fmaxf(mx, v);
    sm += v;
  }
  out[b * 512 + c] = mx;
  out[b * 512 + 256 + c] = sm * (1.0f / 2048.0f);
}

// ---------------------------------------------------------------------------
extern "C" void kernel_launch(void* const* d_in, const int* in_sizes, int n_in,
                              void* d_out, int out_size, void* d_ws, size_t ws_size,
                              hipStream_t stream) {
  const float* x = (const float*)d_in[0];
  const float* W[24];
  for (int i = 0; i < 24; ++i) W[i] = (const float*)d_in[1 + i];

  float* ws = (float*)d_ws;
  size_t off = 0;
  float* partial = ws + off; off += (size_t)NB * NP * 3;
  float* xxbuf = ws + off;   off += TOTPTS;
  int* idxb = (int*)(ws + off); off += (size_t)TOTPTS * KNN;
  float* x1 = ws + off; off += (size_t)TOTPTS * 64;
  float* x2 = ws + off; off += (size_t)TOTPTS * 64;
  float* x3 = ws + off; off += (size_t)TOTPTS * 128;
  float* Uq = ws + off;  off += (size_t)TOTPTS * 128;
  float* Uk = ws + off;  off += (size_t)TOTPTS * 128;
  float* Uv = ws + off;  off += (size_t)TOTPTS * 128;
  float* Uqc = ws + off; off += (size_t)TOTPTS * 128;
  float* Ukc = ws + off; off += (size_t)TOTPTS * 128;
  float* W6 = ws + off;  off += (size_t)TOTPTS * 128;
  // D (NP*NP floats, 16 MB) aliases the U region: each layer's kNN (writes D,
  // reads via select) completes before proj_kernel overwrites Uq. Stream order
  // guarantees this.
  float* D = Uq;
  if (ws_size < off * sizeof(float)) return;  // workspace too small -> clear failure

  fps_kernel<<<NB, 1024, 0, stream>>>(x, partial);

  // -------- layer 1 (C=3, DIM=64)
  xx_kernel<<<TOTPTS / 256, 256, 0, stream>>>(partial, xxbuf, 3);
  for (int b = 0; b < NB; ++b) {
    dist_gemm<3><<<dim3(32, 32), 256, 0, stream>>>(partial, xxbuf, D, b);
    select_kernel<<<NP / 4, 256, 0, stream>>>(D, idxb, b);
  }
  proj_kernel<3, 64><<<TOTPTS / 16, 256, 0, stream>>>(
      partial, partial, W[0], W[1], W[2], W[3], W[4], W[5], W[6], W[7],
      Uq, Uk, Uv, Uqc, Ukc, W6);
  attn_kernel<64><<<TOTPTS / 4, 256, 0, stream>>>(Uq, Uk, Uv, Uqc, Ukc, W6, idxb, x1);

  // -------- layer 2 (C=64, DIM=64)
  xx_kernel<<<TOTPTS / 256, 256, 0, stream>>>(x1, xxbuf, 64);
  for (int b = 0; b < NB; ++b) {
    dist_gemm<64><<<dim3(32, 32), 256, 0, stream>>>(x1, xxbuf, D, b);
    select_kernel<<<NP / 4, 256, 0, stream>>>(D, idxb, b);
  }
  proj_kernel<64, 64><<<TOTPTS / 16, 256, 0, stream>>>(
      x1, partial, W[8], W[9], W[10], W[11], W[12], W[13], W[14], W[15],
      Uq, Uk, Uv, Uqc, Ukc, W6);
  attn_kernel<64><<<TOTPTS / 4, 256, 0, stream>>>(Uq, Uk, Uv, Uqc, Ukc, W6, idxb, x2);

  // -------- layer 3 (C=64, DIM=128)
  xx_kernel<<<TOTPTS / 256, 256, 0, stream>>>(x2, xxbuf, 64);
  for (int b = 0; b < NB; ++b) {
    dist_gemm<64><<<dim3(32, 32), 256, 0, stream>>>(x2, xxbuf, D, b);
    select_kernel<<<NP / 4, 256, 0, stream>>>(D, idxb, b);
  }
  proj_kernel<64, 128><<<TOTPTS / 16, 256, 0, stream>>>(
      x2, partial, W[16], W[17], W[18], W[19], W[20], W[21], W[22], W[23],
      Uq, Uk, Uv, Uqc, Ukc, W6);
  attn_kernel<128><<<TOTPTS / 4, 256, 0, stream>>>(Uq, Uk, Uv, Uqc, Ukc, W6, idxb, x3);

  pool_kernel<<<NB, 256, 0, stream>>>(x1, x2, x3, (float*)d_out);
}

// Round 2
// 5516.501 us; speedup vs baseline: 1.3113x; 1.3113x over previous
//
#include <hip/hip_runtime.h>
#include <math.h>

#define NB 8
#define NIN 16384
#define NP 2048
#define KNN 32
#define TOTPTS (NB * NP)   // 16384

#define NEG_INF (-__builtin_inff())

// ---------------------------------------------------------------------------
// DPP-based wave64 argmax (value float, tie -> lower index). Result lands in
// lane 63 of each wave. Pure VALU (no LDS) — row_shr prefix + row_bcast.
// ---------------------------------------------------------------------------
template <int CTRL, int RMASK>
__device__ __forceinline__ void dpp_amax_step(float& bv, int& bi) {
  float ov = __int_as_float(__builtin_amdgcn_update_dpp(
      __float_as_int(NEG_INF), __float_as_int(bv), CTRL, RMASK, 0xf, false));
  int oi = __builtin_amdgcn_update_dpp(0, bi, CTRL, RMASK, 0xf, false);
  if (ov > bv || (ov == bv && oi < bi)) { bv = ov; bi = oi; }
}

__device__ __forceinline__ void wave_amax63(float& bv, int& bi) {
  dpp_amax_step<0x111, 0xf>(bv, bi);  // row_shr:1
  dpp_amax_step<0x112, 0xf>(bv, bi);  // row_shr:2
  dpp_amax_step<0x114, 0xf>(bv, bi);  // row_shr:4
  dpp_amax_step<0x118, 0xf>(bv, bi);  // row_shr:8
  dpp_amax_step<0x142, 0xa>(bv, bi);  // row_bcast:15 into rows 1,3
  dpp_amax_step<0x143, 0xc>(bv, bi);  // row_bcast:31 into rows 2,3
}

// ---------------------------------------------------------------------------
// FPS: one block per batch, 1024 threads, 16 points/thread (8 x float2).
// Bit-exact vs reference: rn ops, ((dx2+dy2)+dz2), argmax first-index ties.
// One barrier per iteration; inter-wave combine via u64 atomicMax into a
// per-iteration pre-zeroed LDS slot (no reset race).
// ---------------------------------------------------------------------------
__global__ __launch_bounds__(1024) void fps_kernel(const float* __restrict__ x,
                                                   float* __restrict__ partial) {
  const int b = blockIdx.x;
  const int t = threadIdx.x;
  const float* xb = x + (size_t)b * NIN * 3;
  float* pb = partial + (size_t)b * NP * 3;
  __shared__ unsigned long long skey[NP];
  for (int i = t; i < NP; i += 1024) skey[i] = 0ull;

  float2 px[8], py[8], pz[8], dd[8];
#pragma unroll
  for (int j = 0; j < 8; ++j) {
    const int i0 = (2 * j) * 1024 + t, i1 = (2 * j + 1) * 1024 + t;
    px[j] = make_float2(xb[3 * i0], xb[3 * i1]);
    py[j] = make_float2(xb[3 * i0 + 1], xb[3 * i1 + 1]);
    pz[j] = make_float2(xb[3 * i0 + 2], xb[3 * i1 + 2]);
  }
  float qx = xb[0], qy = xb[1], qz = xb[2];
  if (t == 0) { pb[0] = qx; pb[1] = qy; pb[2] = qz; }

  float bv = NEG_INF;
  int bi = 0;
#pragma unroll
  for (int j = 0; j < 8; ++j) {
    float dx = __fsub_rn(px[j].x, qx), dy = __fsub_rn(py[j].x, qy), dz = __fsub_rn(pz[j].x, qz);
    dd[j].x = __fadd_rn(__fadd_rn(__fmul_rn(dx, dx), __fmul_rn(dy, dy)), __fmul_rn(dz, dz));
    if (dd[j].x > bv) { bv = dd[j].x; bi = (2 * j) * 1024 + t; }
    dx = __fsub_rn(px[j].y, qx); dy = __fsub_rn(py[j].y, qy); dz = __fsub_rn(pz[j].y, qz);
    dd[j].y = __fadd_rn(__fadd_rn(__fmul_rn(dx, dx), __fmul_rn(dy, dy)), __fmul_rn(dz, dz));
    if (dd[j].y > bv) { bv = dd[j].y; bi = (2 * j + 1) * 1024 + t; }
  }
  __syncthreads();  // skey init visible before first atomicMax

  for (int it = 1; it < NP; ++it) {
    wave_amax63(bv, bi);
    if ((t & 63) == 63) {
      const unsigned long long key =
          ((unsigned long long)__float_as_uint(bv) << 32) | (unsigned int)(~bi);
      atomicMax(&skey[it], key);
    }
    __syncthreads();
    const unsigned long long gk = skey[it];
    const int gbi = (int)(~(unsigned int)gk);
    const int u = __builtin_amdgcn_readfirstlane(gbi);
    const float nqx = xb[3 * u], nqy = xb[3 * u + 1], nqz = xb[3 * u + 2];
    if (t == 0) { pb[3 * it] = nqx; pb[3 * it + 1] = nqy; pb[3 * it + 2] = nqz; }

    bv = NEG_INF;
    bi = 0;
#pragma unroll
    for (int j = 0; j < 8; ++j) {
      float dx = __fsub_rn(px[j].x, nqx), dy = __fsub_rn(py[j].x, nqy), dz = __fsub_rn(pz[j].x, nqz);
      float nd = __fadd_rn(__fadd_rn(__fmul_rn(dx, dx), __fmul_rn(dy, dy)), __fmul_rn(dz, dz));
      dd[j].x = fminf(dd[j].x, nd);
      if (dd[j].x > bv) { bv = dd[j].x; bi = (2 * j) * 1024 + t; }
      dx = __fsub_rn(px[j].y, nqx); dy = __fsub_rn(py[j].y, nqy); dz = __fsub_rn(pz[j].y, nqz);
      nd = __fadd_rn(__fadd_rn(__fmul_rn(dx, dx), __fmul_rn(dy, dy)), __fmul_rn(dz, dz));
      dd[j].y = fminf(dd[j].y, nd);
      if (dd[j].y > bv) { bv = dd[j].y; bi = (2 * j + 1) * 1024 + t; }
    }
  }
}

// ---------------------------------------------------------------------------
// xx[i] = sum_c F[i][c]^2  (rn, ascending c)
// ---------------------------------------------------------------------------
__global__ void xx_kernel(const float* __restrict__ F, float* __restrict__ xxg, int C) {
  int i = blockIdx.x * 256 + threadIdx.x;
  if (i >= TOTPTS) return;
  const float* f = F + (size_t)i * C;
  float s = 0.f;
  for (int c = 0; c < C; ++c) s = __fadd_rn(s, __fmul_rn(f[c], f[c]));
  xxg[i] = s;
}

// ---------------------------------------------------------------------------
// D[n][m] = (2*<f_n,f_m> - xx[n]) - xx[m]   (neg squared dist).
// batch = bofs + blockIdx.z; D slice = D + blockIdx.z * NP * NP.
// ---------------------------------------------------------------------------
template <int C>
__global__ __launch_bounds__(256) void dist_gemm(const float* __restrict__ F,
                                                 const float* __restrict__ xxg,
                                                 float* __restrict__ D, int bofs) {
  __shared__ float As[64][C + 1];
  __shared__ float Bs[64][C + 1];
  const int b = bofs + blockIdx.z;
  float* Ds = D + (size_t)blockIdx.z * NP * NP;
  const int tid = threadIdx.x;
  const int n0 = blockIdx.y * 64, m0 = blockIdx.x * 64;
  const float* Fb = F + (size_t)b * NP * C;
  const float* xxb = xxg + b * NP;
  for (int t = tid; t < 64 * C; t += 256) {
    int r = t / C, c = t - r * C;
    As[r][c] = Fb[(size_t)(n0 + r) * C + c];
    Bs[r][c] = Fb[(size_t)(m0 + r) * C + c];
  }
  __syncthreads();
  const int tx = tid & 15, ty = tid >> 4;
  float acc[4][4] = {};
  for (int c = 0; c < C; ++c) {
    float a[4], bb[4];
#pragma unroll
    for (int i = 0; i < 4; ++i) a[i] = As[ty * 4 + i][c];
#pragma unroll
    for (int j = 0; j < 4; ++j) bb[j] = Bs[tx * 4 + j][c];
#pragma unroll
    for (int i = 0; i < 4; ++i)
#pragma unroll
      for (int j = 0; j < 4; ++j) acc[i][j] = fmaf(a[i], bb[j], acc[i][j]);
  }
#pragma unroll
  for (int i = 0; i < 4; ++i) {
    int n = n0 + ty * 4 + i;
    float xn = xxb[n];
    float4 o;
    o.x = __fsub_rn(__fsub_rn(2.0f * acc[i][0], xn), xxb[m0 + tx * 4 + 0]);
    o.y = __fsub_rn(__fsub_rn(2.0f * acc[i][1], xn), xxb[m0 + tx * 4 + 1]);
    o.z = __fsub_rn(__fsub_rn(2.0f * acc[i][2], xn), xxb[m0 + tx * 4 + 2]);
    o.w = __fsub_rn(__fsub_rn(2.0f * acc[i][3], xn), xxb[m0 + tx * 4 + 3]);
    *(float4*)&Ds[(size_t)n * NP + m0 + tx * 4] = o;
  }
}

// ---------------------------------------------------------------------------
// top-32 (by value, ties -> lower index) per row; one wave per row.
// DPP argmax instead of shfl (no LDS ops in the extraction chain).
// ---------------------------------------------------------------------------
__global__ __launch_bounds__(256) void select_kernel(const float* __restrict__ D,
                                                     int* __restrict__ idxg, int bofs) {
  const int lane = threadIdx.x & 63;
  const int b = bofs + blockIdx.z;
  const int row = blockIdx.x * 4 + (threadIdx.x >> 6);
  const float* Drow = D + (size_t)blockIdx.z * NP * NP + (size_t)row * NP;
  float v[32];
#pragma unroll
  for (int s = 0; s < 32; ++s) v[s] = Drow[s * 64 + lane];
  int* out = idxg + ((size_t)b * NP + row) * KNN;
  for (int t = 0; t < KNN; ++t) {
    float bv = v[0];
    int bs = 0;
#pragma unroll
    for (int s = 1; s < 32; ++s) {
      if (v[s] > bv) { bv = v[s]; bs = s; }
    }
    int bi = bs * 64 + lane;
    wave_amax63(bv, bi);
    const int wbi = __builtin_amdgcn_readlane(bi, 63);
    if (lane == 0) out[t] = wbi;
    const bool own = (lane == (wbi & 63));
    const int cs = wbi >> 6;
#pragma unroll
    for (int s = 0; s < 32; ++s)
      if (own && s == cs) v[s] = NEG_INF;
  }
}

// ---------------------------------------------------------------------------
// Per-point projections: Uq = Wq1*x, Uqc = (Wq2-Wq1)*x + bq (same for K),
// Uv = Wv1*x, W6 = (Wv2-Wv1)*x + bv + (Wp*pos + bp).
// ---------------------------------------------------------------------------
template <int C, int DIM>
__global__ __launch_bounds__(256) void proj_kernel(
    const float* __restrict__ F, const float* __restrict__ pos,
    const float* __restrict__ Wq, const float* __restrict__ bq,
    const float* __restrict__ Wk, const float* __restrict__ bk,
    const float* __restrict__ Wv, const float* __restrict__ bv,
    const float* __restrict__ Wp, const float* __restrict__ bp,
    float* __restrict__ Uq, float* __restrict__ Uk, float* __restrict__ Uv,
    float* __restrict__ Uqc, float* __restrict__ Ukc, float* __restrict__ W6) {
  constexpr int PTS = 16;
  constexpr int GROUPS = 256 / DIM;
  constexpr int PPT = PTS / GROUPS;
  __shared__ float xs[PTS][C];
  __shared__ float ps[PTS][3];
  const int tid = threadIdx.x;
  const int base = blockIdx.x * PTS;
  for (int t = tid; t < PTS * C; t += 256) {
    int r = t / C;
    xs[r][t - r * C] = F[(size_t)(base + r) * C + (t - r * C)];
  }
  for (int t = tid; t < PTS * 3; t += 256) {
    int r = t / 3;
    ps[r][t - r * 3] = pos[(size_t)(base + r) * 3 + (t - r * 3)];
  }
  __syncthreads();
  const int g = tid / DIM;
  const int d = tid - g * DIM;
  float uq[PPT], uqd[PPT], uk[PPT], ukd[PPT], uv[PPT], uvd[PPT];
#pragma unroll
  for (int p = 0; p < PPT; ++p) { uq[p] = uqd[p] = uk[p] = ukd[p] = uv[p] = uvd[p] = 0.f; }
  const float* wqr = Wq + (size_t)d * (2 * C);
  const float* wkr = Wk + (size_t)d * (2 * C);
  const float* wvr = Wv + (size_t)d * (2 * C);
  for (int c = 0; c < C; ++c) {
    const float wq1 = wqr[c], wqd_ = wqr[C + c] - wq1;
    const float wk1 = wkr[c], wkd_ = wkr[C + c] - wk1;
    const float wv1 = wvr[c], wvd_ = wvr[C + c] - wv1;
#pragma unroll
    for (int p = 0; p < PPT; ++p) {
      const float xc = xs[g + p * GROUPS][c];
      uq[p] = fmaf(wq1, xc, uq[p]);
      uqd[p] = fmaf(wqd_, xc, uqd[p]);
      uk[p] = fmaf(wk1, xc, uk[p]);
      ukd[p] = fmaf(wkd_, xc, ukd[p]);
      uv[p] = fmaf(wv1, xc, uv[p]);
      uvd[p] = fmaf(wvd_, xc, uvd[p]);
    }
  }
  const float bqd = bq[d], bkd = bk[d], bvd = bv[d];
  const float wp0 = Wp[d * 3], wp1 = Wp[d * 3 + 1], wp2 = Wp[d * 3 + 2], bpd = bp[d];
#pragma unroll
  for (int p = 0; p < PPT; ++p) {
    const int lp = g + p * GROUPS;
    const size_t o = (size_t)(base + lp) * DIM + d;
    const float pd = wp0 * ps[lp][0] + wp1 * ps[lp][1] + wp2 * ps[lp][2] + bpd;
    Uq[o] = uq[p];
    Uqc[o] = uqd[p] + bqd;
    Uk[o] = uk[p];
    Ukc[o] = ukd[p] + bkd;
    Uv[o] = uv[p];
    W6[o] = uvd[p] + bvd + pd;
  }
}

// ---------------------------------------------------------------------------
// Attention: per point, logits_k = <Uq[ik]+Uqc[n], Uk[ik]+Ukc[n]>/sqrt(DIM),
// softmax over k, out_d = sum_k attn_k * (Uv[ik][d] + W6[n][d]).
// One wave per point, 4 points per block.
// ---------------------------------------------------------------------------
template <int DIM>
__global__ __launch_bounds__(256) void attn_kernel(
    const float* __restrict__ Uq, const float* __restrict__ Uk, const float* __restrict__ Uv,
    const float* __restrict__ Uqc, const float* __restrict__ Ukc, const float* __restrict__ W6g,
    const int* __restrict__ idxg, float* __restrict__ outF) {
  const int w = threadIdx.x >> 6, lane = threadIdx.x & 63;
  const int pt = blockIdx.x * 4 + w;
  const int b = pt >> 11;
  __shared__ int sidx[4][KNN];
  __shared__ float sqc[4][DIM], skc[4][DIM], sw6[4][DIM];
  __shared__ float sattn[4][KNN];
  const size_t rowo = (size_t)pt * DIM;
  if (lane < KNN) sidx[w][lane] = idxg[(size_t)pt * KNN + lane];
  for (int d = lane; d < DIM; d += 64) {
    sqc[w][d] = Uqc[rowo + d];
    skc[w][d] = Ukc[rowo + d];
    sw6[w][d] = W6g[rowo + d];
  }
  __syncthreads();
  if (lane < KNN) {
    const int ik = sidx[w][lane];
    const float* qr = Uq + (size_t)(b * NP + ik) * DIM;
    const float* kr = Uk + (size_t)(b * NP + ik) * DIM;
    float lg = 0.f;
    for (int d = 0; d < DIM; d += 4) {
      float4 qa = *(const float4*)(qr + d);
      float4 ka = *(const float4*)(kr + d);
      float4 qc = *(const float4*)(&sqc[w][d]);
      float4 kc = *(const float4*)(&skc[w][d]);
      lg += (qa.x + qc.x) * (ka.x + kc.x);
      lg += (qa.y + qc.y) * (ka.y + kc.y);
      lg += (qa.z + qc.z) * (ka.z + kc.z);
      lg += (qa.w + qc.w) * (ka.w + kc.w);
    }
    lg /= sqrtf((float)DIM);
    float m = lg;
#pragma unroll
    for (int off = 16; off; off >>= 1) m = fmaxf(m, __shfl_xor(m, off));
    float e = expf(lg - m);
    float s = e;
#pragma unroll
    for (int off = 16; off; off >>= 1) s += __shfl_xor(s, off);
    sattn[w][lane] = e / s;
  }
  __syncthreads();
  float acc[DIM / 64];
#pragma unroll
  for (int q = 0; q < DIM / 64; ++q) acc[q] = 0.f;
  for (int k = 0; k < KNN; ++k) {
    const int ik = sidx[w][k];
    const float a = sattn[w][k];
    const float* vr = Uv + (size_t)(b * NP + ik) * DIM;
#pragma unroll
    for (int q = 0; q < DIM / 64; ++q) {
      const int d = q * 64 + lane;
      acc[q] = fmaf(a, vr[d] + sw6[w][d], acc[q]);
    }
  }
#pragma unroll
  for (int q = 0; q < DIM / 64; ++q) outF[rowo + q * 64 + lane] = acc[q];
}

// ---------------------------------------------------------------------------
// Pooling: out[b][c] = max_n feats, out[b][256+c] = mean_n feats.
// ---------------------------------------------------------------------------
__global__ __launch_bounds__(256) void pool_kernel(const float* __restrict__ x1,
                                                   const float* __restrict__ x2,
                                                   const float* __restrict__ x3,
                                                   float* __restrict__ out) {
  const int b = blockIdx.x, c = threadIdx.x;
  const float* src;
  int dim, cl;
  if (c < 64) {
    src = x1 + (size_t)b * NP * 64; dim = 64; cl = c;
  } else if (c < 128) {
    src = x2 + (size_t)b * NP * 64; dim = 64; cl = c - 64;
  } else {
    src = x3 + (size_t)b * NP * 128; dim = 128; cl = c - 128;
  }
  float mx = NEG_INF, sm = 0.f;
#pragma unroll 8
  for (int n = 0; n < NP; ++n) {
    float v = src[(size_t)n * dim + cl];
    mx = fmaxf(mx, v);
    sm += v;
  }
  out[b * 512 + c] = mx;
  out[b * 512 + 256 + c] = sm * (1.0f / 2048.0f);
}

// ---------------------------------------------------------------------------
extern "C" void kernel_launch(void* const* d_in, const int* in_sizes, int n_in,
                              void* d_out, int out_size, void* d_ws, size_t ws_size,
                              hipStream_t stream) {
  const float* x = (const float*)d_in[0];
  const float* W[24];
  for (int i = 0; i < 24; ++i) W[i] = (const float*)d_in[1 + i];

  float* ws = (float*)d_ws;
  size_t off = 0;
  float* partial = ws + off; off += (size_t)NB * NP * 3;
  float* xxbuf = ws + off;   off += TOTPTS;
  int* idxb = (int*)(ws + off); off += (size_t)TOTPTS * KNN;
  float* x1 = ws + off; off += (size_t)TOTPTS * 64;
  float* x2 = ws + off; off += (size_t)TOTPTS * 64;
  float* x3 = ws + off; off += (size_t)TOTPTS * 128;
  float* Uq = ws + off;  off += (size_t)TOTPTS * 128;
  float* Uk = ws + off;  off += (size_t)TOTPTS * 128;
  float* Uv = ws + off;  off += (size_t)TOTPTS * 128;
  float* Uqc = ws + off; off += (size_t)TOTPTS * 128;
  float* Ukc = ws + off; off += (size_t)TOTPTS * 128;
  float* W6 = ws + off;  off += (size_t)TOTPTS * 128;
  if (ws_size < off * sizeof(float)) return;

  // Big-workspace path: all 8 batches' D slices live simultaneously so
  // dist_gemm/select run as single z-batched dispatches (8x fewer launches,
  // full-GPU occupancy). Fallback: D aliases Uq+Uk (16 MB), per-batch loop.
  float* Dbig = ws + off;
  const size_t need_big = (off + (size_t)NB * NP * NP) * sizeof(float);
  const bool bigws = (ws_size >= need_big);
  float* D = bigws ? Dbig : Uq;
  const int NZ = bigws ? NB : 1;

  fps_kernel<<<NB, 1024, 0, stream>>>(x, partial);

  // -------- layer 1 (C=3, DIM=64)
  xx_kernel<<<TOTPTS / 256, 256, 0, stream>>>(partial, xxbuf, 3);
  for (int b = 0; b < NB; b += NZ) {
    dist_gemm<3><<<dim3(32, 32, NZ), 256, 0, stream>>>(partial, xxbuf, D, b);
    select_kernel<<<dim3(NP / 4, 1, NZ), 256, 0, stream>>>(D, idxb, b);
  }
  proj_kernel<3, 64><<<TOTPTS / 16, 256, 0, stream>>>(
      partial, partial, W[0], W[1], W[2], W[3], W[4], W[5], W[6], W[7],
      Uq, Uk, Uv, Uqc, Ukc, W6);
  attn_kernel<64><<<TOTPTS / 4, 256, 0, stream>>>(Uq, Uk, Uv, Uqc, Ukc, W6, idxb, x1);

  // -------- layer 2 (C=64, DIM=64)
  xx_kernel<<<TOTPTS / 256, 256, 0, stream>>>(x1, xxbuf, 64);
  for (int b = 0; b < NB; b += NZ) {
    dist_gemm<64><<<dim3(32, 32, NZ), 256, 0, stream>>>(x1, xxbuf, D, b);
    select_kernel<<<dim3(NP / 4, 1, NZ), 256, 0, stream>>>(D, idxb, b);
  }
  proj_kernel<64, 64><<<TOTPTS / 16, 256, 0, stream>>>(
      x1, partial, W[8], W[9], W[10], W[11], W[12], W[13], W[14], W[15],
      Uq, Uk, Uv, Uqc, Ukc, W6);
  attn_kernel<64><<<TOTPTS / 4, 256, 0, stream>>>(Uq, Uk, Uv, Uqc, Ukc, W6, idxb, x2);

  // -------- layer 3 (C=64, DIM=128)
  xx_kernel<<<TOTPTS / 256, 256, 0, stream>>>(x2, xxbuf, 64);
  for (int b = 0; b < NB; b += NZ) {
    dist_gemm<64><<<dim3(32, 32, NZ), 256, 0, stream>>>(x2, xxbuf, D, b);
    select_kernel<<<dim3(NP / 4, 1, NZ), 256, 0, stream>>>(D, idxb, b);
  }
  proj_kernel<64, 128><<<TOTPTS / 16, 256, 0, stream>>>(
      x2, partial, W[16], W[17], W[18], W[19], W[20], W[21], W[22], W[23],
      Uq, Uk, Uv, Uqc, Ukc, W6);
  attn_kernel<128><<<TOTPTS / 4, 256, 0, stream>>>(Uq, Uk, Uv, Uqc, Ukc, W6, idxb, x3);

  pool_kernel<<<NB, 256, 0, stream>>>(x1, x2, x3, (float*)d_out);
}

// Round 4
// 4815.934 us; speedup vs baseline: 1.5021x; 1.1455x over previous
//
#include <hip/hip_runtime.h>
#include <math.h>

#define NB 8
#define NIN 16384
#define NP 2048
#define KNN 32
#define TOTPTS (NB * NP)   // 16384

#define NEG_INF (-__builtin_inff())

// ---------------------------------------------------------------------------
// Packed fp32 ops (VOP3P): 2 rounds-to-nearest f32 ops per instruction.
// Bit-exact to __fadd_rn / __fmul_rn on each half.
// ---------------------------------------------------------------------------
__device__ __forceinline__ float2 pk_add(float2 a, float2 b) {
  float2 d;
  asm("v_pk_add_f32 %0, %1, %2" : "=v"(d) : "v"(a), "v"(b));
  return d;
}
__device__ __forceinline__ float2 pk_mul(float2 a, float2 b) {
  float2 d;
  asm("v_pk_mul_f32 %0, %1, %2" : "=v"(d) : "v"(a), "v"(b));
  return d;
}

// ---------------------------------------------------------------------------
// DPP wave64 reductions; result valid in lane 63.
// ---------------------------------------------------------------------------
#define DPP_F(old, v, C, RM) \
  __int_as_float(__builtin_amdgcn_update_dpp(__float_as_int(old), __float_as_int(v), C, RM, 0xf, false))
#define DPP_I(old, v, C, RM) \
  __builtin_amdgcn_update_dpp(old, v, C, RM, 0xf, false)

__device__ __forceinline__ float wave_max_f(float v) {
  v = fmaxf(v, DPP_F(NEG_INF, v, 0x111, 0xf));
  v = fmaxf(v, DPP_F(NEG_INF, v, 0x112, 0xf));
  v = fmaxf(v, DPP_F(NEG_INF, v, 0x114, 0xf));
  v = fmaxf(v, DPP_F(NEG_INF, v, 0x118, 0xf));
  v = fmaxf(v, DPP_F(NEG_INF, v, 0x142, 0xa));
  v = fmaxf(v, DPP_F(NEG_INF, v, 0x143, 0xc));
  return v;
}
__device__ __forceinline__ int wave_min_i(int v) {
  v = min(v, DPP_I(0x7fffffff, v, 0x111, 0xf));
  v = min(v, DPP_I(0x7fffffff, v, 0x112, 0xf));
  v = min(v, DPP_I(0x7fffffff, v, 0x114, 0xf));
  v = min(v, DPP_I(0x7fffffff, v, 0x118, 0xf));
  v = min(v, DPP_I(0x7fffffff, v, 0x142, 0xa));
  v = min(v, DPP_I(0x7fffffff, v, 0x143, 0xc));
  return v;
}

// combined (value,index) argmax to lane63 — used by select_kernel
template <int CTRL, int RMASK>
__device__ __forceinline__ void dpp_amax_step(float& bv, int& bi) {
  float ov = DPP_F(NEG_INF, bv, CTRL, RMASK);
  int oi = DPP_I(0, bi, CTRL, RMASK);
  if (ov > bv || (ov == bv && oi < bi)) { bv = ov; bi = oi; }
}
__device__ __forceinline__ void wave_amax63(float& bv, int& bi) {
  dpp_amax_step<0x111, 0xf>(bv, bi);
  dpp_amax_step<0x112, 0xf>(bv, bi);
  dpp_amax_step<0x114, 0xf>(bv, bi);
  dpp_amax_step<0x118, 0xf>(bv, bi);
  dpp_amax_step<0x142, 0xa>(bv, bi);
  dpp_amax_step<0x143, 0xc>(bv, bi);
}

// ---------------------------------------------------------------------------
// FPS: one block per batch, 1024 threads, 16 points/thread (8 x float2).
// Packed-fp32 distance math (bit-exact rn), fused argmax (lowest-index ties),
// value-max DPP + min-index DPP wave reduce, u64 atomicMax block combine.
// ---------------------------------------------------------------------------
__global__ __launch_bounds__(1024) void fps_kernel(const float* __restrict__ x,
                                                   float* __restrict__ partial) {
  const int b = blockIdx.x;
  const int t = threadIdx.x;
  const float* xb = x + (size_t)b * NIN * 3;
  float* pb = partial + (size_t)b * NP * 3;
  __shared__ unsigned long long skey[NP];
  for (int i = t; i < NP; i += 1024) skey[i] = 0ull;

  float2 px[8], py[8], pz[8], dd[8];
#pragma unroll
  for (int j = 0; j < 8; ++j) {
    const int i0 = (2 * j) * 1024 + t, i1 = (2 * j + 1) * 1024 + t;
    px[j] = make_float2(xb[3 * i0], xb[3 * i1]);
    py[j] = make_float2(xb[3 * i0 + 1], xb[3 * i1 + 1]);
    pz[j] = make_float2(xb[3 * i0 + 2], xb[3 * i1 + 2]);
  }
  const float qx0 = xb[0], qy0 = xb[1], qz0 = xb[2];
  if (t == 0) { pb[0] = qx0; pb[1] = qy0; pb[2] = qz0; }

  float bv = NEG_INF;
  int bi = 0;
  {
    const float2 nx2 = make_float2(-qx0, -qx0);
    const float2 ny2 = make_float2(-qy0, -qy0);
    const float2 nz2 = make_float2(-qz0, -qz0);
#pragma unroll
    for (int j = 0; j < 8; ++j) {
      float2 dx = pk_add(px[j], nx2), dy = pk_add(py[j], ny2), dz = pk_add(pz[j], nz2);
      float2 nd = pk_add(pk_add(pk_mul(dx, dx), pk_mul(dy, dy)), pk_mul(dz, dz));
      dd[j] = nd;
      if (nd.x > bv) { bv = nd.x; bi = (2 * j) * 1024 + t; }
      if (nd.y > bv) { bv = nd.y; bi = (2 * j + 1) * 1024 + t; }
    }
  }
  __syncthreads();  // skey init visible before first atomicMax

  for (int it = 1; it < NP; ++it) {
    // wave reduce: value max, then lowest index among value-matching lanes
    const float wm = wave_max_f(bv);
    const float smax = __int_as_float(__builtin_amdgcn_readlane(__float_as_int(wm), 63));
    const int sel = (bv == smax) ? bi : 0x7fffffff;
    const int wi = wave_min_i(sel);
    if ((t & 63) == 63) {
      const unsigned long long key =
          ((unsigned long long)__float_as_uint(smax) << 32) | (unsigned int)(~wi);
      atomicMax(&skey[it], key);
    }
    __syncthreads();
    const unsigned long long gk = skey[it];
    const int gbi = (int)(~(unsigned int)gk);
    const int u = __builtin_amdgcn_readfirstlane(gbi);
    const float nqx = xb[3 * u], nqy = xb[3 * u + 1], nqz = xb[3 * u + 2];
    if (t == 0) { pb[3 * it] = nqx; pb[3 * it + 1] = nqy; pb[3 * it + 2] = nqz; }

    const float2 nx2 = make_float2(-nqx, -nqx);
    const float2 ny2 = make_float2(-nqy, -nqy);
    const float2 nz2 = make_float2(-nqz, -nqz);
    bv = NEG_INF;
    bi = 0;
#pragma unroll
    for (int j = 0; j < 8; ++j) {
      float2 dx = pk_add(px[j], nx2), dy = pk_add(py[j], ny2), dz = pk_add(pz[j], nz2);
      float2 nd = pk_add(pk_add(pk_mul(dx, dx), pk_mul(dy, dy)), pk_mul(dz, dz));
      const float a0 = fminf(dd[j].x, nd.x);
      dd[j].x = a0;
      if (a0 > bv) { bv = a0; bi = (2 * j) * 1024 + t; }
      const float a1 = fminf(dd[j].y, nd.y);
      dd[j].y = a1;
      if (a1 > bv) { bv = a1; bi = (2 * j + 1) * 1024 + t; }
    }
  }
}

// ---------------------------------------------------------------------------
// xx[i] = sum_c F[i][c]^2  (rn, ascending c)
// ---------------------------------------------------------------------------
__global__ void xx_kernel(const float* __restrict__ F, float* __restrict__ xxg, int C) {
  int i = blockIdx.x * 256 + threadIdx.x;
  if (i >= TOTPTS) return;
  const float* f = F + (size_t)i * C;
  float s = 0.f;
  for (int c = 0; c < C; ++c) s = __fadd_rn(s, __fmul_rn(f[c], f[c]));
  xxg[i] = s;
}

// ---------------------------------------------------------------------------
// D[n][m] = (2*<f_n,f_m> - xx[n]) - xx[m]   (neg squared dist).
// ---------------------------------------------------------------------------
template <int C>
__global__ __launch_bounds__(256) void dist_gemm(const float* __restrict__ F,
                                                 const float* __restrict__ xxg,
                                                 float* __restrict__ D, int bofs) {
  __shared__ float As[64][C + 1];
  __shared__ float Bs[64][C + 1];
  const int b = bofs + blockIdx.z;
  float* Ds = D + (size_t)blockIdx.z * NP * NP;
  const int tid = threadIdx.x;
  const int n0 = blockIdx.y * 64, m0 = blockIdx.x * 64;
  const float* Fb = F + (size_t)b * NP * C;
  const float* xxb = xxg + b * NP;
  for (int t = tid; t < 64 * C; t += 256) {
    int r = t / C, c = t - r * C;
    As[r][c] = Fb[(size_t)(n0 + r) * C + c];
    Bs[r][c] = Fb[(size_t)(m0 + r) * C + c];
  }
  __syncthreads();
  const int tx = tid & 15, ty = tid >> 4;
  float acc[4][4] = {};
  for (int c = 0; c < C; ++c) {
    float a[4], bb[4];
#pragma unroll
    for (int i = 0; i < 4; ++i) a[i] = As[ty * 4 + i][c];
#pragma unroll
    for (int j = 0; j < 4; ++j) bb[j] = Bs[tx * 4 + j][c];
#pragma unroll
    for (int i = 0; i < 4; ++i)
#pragma unroll
      for (int j = 0; j < 4; ++j) acc[i][j] = fmaf(a[i], bb[j], acc[i][j]);
  }
#pragma unroll
  for (int i = 0; i < 4; ++i) {
    int n = n0 + ty * 4 + i;
    float xn = xxb[n];
    float4 o;
    o.x = __fsub_rn(__fsub_rn(2.0f * acc[i][0], xn), xxb[m0 + tx * 4 + 0]);
    o.y = __fsub_rn(__fsub_rn(2.0f * acc[i][1], xn), xxb[m0 + tx * 4 + 1]);
    o.z = __fsub_rn(__fsub_rn(2.0f * acc[i][2], xn), xxb[m0 + tx * 4 + 2]);
    o.w = __fsub_rn(__fsub_rn(2.0f * acc[i][3], xn), xxb[m0 + tx * 4 + 3]);
    *(float4*)&Ds[(size_t)n * NP + m0 + tx * 4] = o;
  }
}

// ---------------------------------------------------------------------------
// top-32 (value desc, ties -> lower index) per row; one wave per row.
// ---------------------------------------------------------------------------
__global__ __launch_bounds__(256) void select_kernel(const float* __restrict__ D,
                                                     int* __restrict__ idxg, int bofs) {
  const int lane = threadIdx.x & 63;
  const int b = bofs + blockIdx.z;
  const int row = blockIdx.x * 4 + (threadIdx.x >> 6);
  const float* Drow = D + (size_t)blockIdx.z * NP * NP + (size_t)row * NP;
  float v[32];
#pragma unroll
  for (int s = 0; s < 32; ++s) v[s] = Drow[s * 64 + lane];
  int* out = idxg + ((size_t)b * NP + row) * KNN;
  for (int t = 0; t < KNN; ++t) {
    float bv = v[0];
    int bs = 0;
#pragma unroll
    for (int s = 1; s < 32; ++s) {
      if (v[s] > bv) { bv = v[s]; bs = s; }
    }
    int bi = bs * 64 + lane;
    wave_amax63(bv, bi);
    const int wbi = __builtin_amdgcn_readlane(bi, 63);
    if (lane == 0) out[t] = wbi;
    const bool own = (lane == (wbi & 63));
    const int cs = wbi >> 6;
#pragma unroll
    for (int s = 0; s < 32; ++s)
      if (own && s == cs) v[s] = NEG_INF;
  }
}

// ---------------------------------------------------------------------------
// Layer-1 projections (C=3): per-point gather form (cheap at K=3).
// ---------------------------------------------------------------------------
template <int C, int DIM>
__global__ __launch_bounds__(256) void proj_kernel(
    const float* __restrict__ F, const float* __restrict__ pos,
    const float* __restrict__ Wq, const float* __restrict__ bq,
    const float* __restrict__ Wk, const float* __restrict__ bk,
    const float* __restrict__ Wv, const float* __restrict__ bv,
    const float* __restrict__ Wp, const float* __restrict__ bp,
    float* __restrict__ Uq, float* __restrict__ Uk, float* __restrict__ Uv,
    float* __restrict__ Uqc, float* __restrict__ Ukc, float* __restrict__ W6) {
  constexpr int PTS = 16;
  constexpr int GROUPS = 256 / DIM;
  constexpr int PPT = PTS / GROUPS;
  __shared__ float xs[PTS][C];
  __shared__ float ps[PTS][3];
  const int tid = threadIdx.x;
  const int base = blockIdx.x * PTS;
  for (int t = tid; t < PTS * C; t += 256) {
    int r = t / C;
    xs[r][t - r * C] = F[(size_t)(base + r) * C + (t - r * C)];
  }
  for (int t = tid; t < PTS * 3; t += 256) {
    int r = t / 3;
    ps[r][t - r * 3] = pos[(size_t)(base + r) * 3 + (t - r * 3)];
  }
  __syncthreads();
  const int g = tid / DIM;
  const int d = tid - g * DIM;
  float uq[PPT], uqd[PPT], uk[PPT], ukd[PPT], uv[PPT], uvd[PPT];
#pragma unroll
  for (int p = 0; p < PPT; ++p) { uq[p] = uqd[p] = uk[p] = ukd[p] = uv[p] = uvd[p] = 0.f; }
  const float* wqr = Wq + (size_t)d * (2 * C);
  const float* wkr = Wk + (size_t)d * (2 * C);
  const float* wvr = Wv + (size_t)d * (2 * C);
  for (int c = 0; c < C; ++c) {
    const float wq1 = wqr[c], wqd_ = wqr[C + c] - wq1;
    const float wk1 = wkr[c], wkd_ = wkr[C + c] - wk1;
    const float wv1 = wvr[c], wvd_ = wvr[C + c] - wv1;
#pragma unroll
    for (int p = 0; p < PPT; ++p) {
      const float xc = xs[g + p * GROUPS][c];
      uq[p] = fmaf(wq1, xc, uq[p]);
      uqd[p] = fmaf(wqd_, xc, uqd[p]);
      uk[p] = fmaf(wk1, xc, uk[p]);
      ukd[p] = fmaf(wkd_, xc, ukd[p]);
      uv[p] = fmaf(wv1, xc, uv[p]);
      uvd[p] = fmaf(wvd_, xc, uvd[p]);
    }
  }
  const float bqd = bq[d], bkd = bk[d], bvd = bv[d];
  const float wp0 = Wp[d * 3], wp1 = Wp[d * 3 + 1], wp2 = Wp[d * 3 + 2], bpd = bp[d];
#pragma unroll
  for (int p = 0; p < PPT; ++p) {
    const int lp = g + p * GROUPS;
    const size_t o = (size_t)(base + lp) * DIM + d;
    const float pd = wp0 * ps[lp][0] + wp1 * ps[lp][1] + wp2 * ps[lp][2] + bpd;
    Uq[o] = uq[p];
    Uqc[o] = uqd[p] + bqd;
    Uk[o] = uk[p];
    Ukc[o] = ukd[p] + bkd;
    Uv[o] = uv[p];
    W6[o] = uvd[p] + bvd + pd;
  }
}

// ---------------------------------------------------------------------------
// prep: Wcat[c][o] (c<64, o<6*DIM) = [Wq1|Wqd|Wk1|Wkd|Wv1|Wvd] transposed;
// bcat[o] = [0|bq|0|bk|0|bv]. Same (w2-w1) subtraction as proj_kernel.
// ---------------------------------------------------------------------------
template <int DIM>
__global__ void prep_kernel(const float* __restrict__ Wq, const float* __restrict__ bq,
                            const float* __restrict__ Wk, const float* __restrict__ bk,
                            const float* __restrict__ Wv, const float* __restrict__ bv,
                            float* __restrict__ Wcat, float* __restrict__ bcat) {
  const int o = blockIdx.x * 256 + threadIdx.x;
  constexpr int ND = 6 * DIM;
  if (o >= ND) return;
  const int blk = o / DIM, d = o % DIM;
  bcat[o] = (blk == 1) ? bq[d] : (blk == 3) ? bk[d] : (blk == 5) ? bv[d] : 0.f;
  const float* W = (blk < 2) ? Wq : (blk < 4) ? Wk : Wv;
  for (int c = 0; c < 64; ++c) {
    const float w1 = W[(size_t)d * 128 + c];
    const float w2 = W[(size_t)d * 128 + 64 + c];
    Wcat[(size_t)c * ND + o] = (blk & 1) ? (w2 - w1) : w1;
  }
}

// ---------------------------------------------------------------------------
// pos proj: P[pt][d] = Wp[d]·pos[pt] + bp[d]
// ---------------------------------------------------------------------------
template <int DIM>
__global__ void pos_kernel(const float* __restrict__ pos, const float* __restrict__ Wp,
                           const float* __restrict__ bp, float* __restrict__ P) {
  const int idx = blockIdx.x * 256 + threadIdx.x;
  const int pt = idx / DIM, d = idx - pt * DIM;
  P[idx] = Wp[d * 3] * pos[pt * 3] + Wp[d * 3 + 1] * pos[pt * 3 + 1] +
           Wp[d * 3 + 2] * pos[pt * 3 + 2] + bp[d];
}

// ---------------------------------------------------------------------------
// proj GEMM (layers 2/3, K=64): out[64pts x 64cols] per block, 4x4 micro-tile.
// As[pt][k], Bs[k][col] — note bb reads Bs[c][col] (r3 bug was Bs[col][c]).
// Col-block -> one of {Uq,Uqc,Uk,Ukc,Uv,W6}; W6 adds pos-proj P.
// ---------------------------------------------------------------------------
template <int DIM>
__global__ __launch_bounds__(256) void gemm_proj(
    const float* __restrict__ F, const float* __restrict__ Wcat,
    const float* __restrict__ bcat, const float* __restrict__ P,
    float* __restrict__ Uq, float* __restrict__ Uqc, float* __restrict__ Uk,
    float* __restrict__ Ukc, float* __restrict__ Uv, float* __restrict__ W6) {
  constexpr int ND = 6 * DIM;
  __shared__ float As[64][65];
  __shared__ float Bs[64][65];
  const int tid = threadIdx.x;
  const int p0 = blockIdx.x * 64;
  const int n0 = blockIdx.y * 64;
  {
    const int r0 = tid >> 4, c4 = (tid & 15) * 4;
    for (int r = r0; r < 64; r += 16) {
      float4 a = *(const float4*)&F[(size_t)(p0 + r) * 64 + c4];
      As[r][c4] = a.x; As[r][c4 + 1] = a.y; As[r][c4 + 2] = a.z; As[r][c4 + 3] = a.w;
      float4 bb = *(const float4*)&Wcat[(size_t)r * ND + n0 + c4];
      Bs[r][c4] = bb.x; Bs[r][c4 + 1] = bb.y; Bs[r][c4 + 2] = bb.z; Bs[r][c4 + 3] = bb.w;
    }
  }
  __syncthreads();
  const int tx = tid & 15, ty = tid >> 4;
  float acc[4][4] = {};
#pragma unroll 4
  for (int c = 0; c < 64; ++c) {
    float a[4], bb[4];
#pragma unroll
    for (int i = 0; i < 4; ++i) a[i] = As[ty * 4 + i][c];
#pragma unroll
    for (int j = 0; j < 4; ++j) bb[j] = Bs[c][tx * 4 + j];   // FIXED: B is [k][col]
#pragma unroll
    for (int i = 0; i < 4; ++i)
#pragma unroll
      for (int j = 0; j < 4; ++j) acc[i][j] = fmaf(a[i], bb[j], acc[i][j]);
  }
  const int obuf = n0 / DIM;
  const int oloc = n0 - obuf * DIM;
  float* outp = (obuf == 0) ? Uq : (obuf == 1) ? Uqc : (obuf == 2) ? Uk
              : (obuf == 3) ? Ukc : (obuf == 4) ? Uv : W6;
  const float b0 = bcat[n0 + tx * 4], b1 = bcat[n0 + tx * 4 + 1];
  const float b2 = bcat[n0 + tx * 4 + 2], b3 = bcat[n0 + tx * 4 + 3];
#pragma unroll
  for (int i = 0; i < 4; ++i) {
    const int p = p0 + ty * 4 + i;
    float4 r = make_float4(acc[i][0] + b0, acc[i][1] + b1, acc[i][2] + b2, acc[i][3] + b3);
    if (obuf == 5) {
      float4 pv = *(const float4*)&P[(size_t)p * DIM + oloc + tx * 4];
      r.x += pv.x; r.y += pv.y; r.z += pv.z; r.w += pv.w;
    }
    *(float4*)&outp[(size_t)p * DIM + oloc + tx * 4] = r;
  }
}

// ---------------------------------------------------------------------------
// Attention. QK: all 64 lanes (lane = k + 32*dhalf), one shfl_xor(32) combine.
// PV: lane = d (coalesced row loads).
// ---------------------------------------------------------------------------
template <int DIM>
__global__ __launch_bounds__(256) void attn_kernel(
    const float* __restrict__ Uq, const float* __restrict__ Uk, const float* __restrict__ Uv,
    const float* __restrict__ Uqc, const float* __restrict__ Ukc, const float* __restrict__ W6g,
    const int* __restrict__ idxg, float* __restrict__ outF) {
  const int w = threadIdx.x >> 6, lane = threadIdx.x & 63;
  const int pt = blockIdx.x * 4 + w;
  const int b = pt >> 11;
  __shared__ int sidx[4][KNN];
  __shared__ float sqc[4][DIM], skc[4][DIM], sw6[4][DIM];
  __shared__ float sattn[4][KNN];
  const size_t rowo = (size_t)pt * DIM;
  if (lane < KNN) sidx[w][lane] = idxg[(size_t)pt * KNN + lane];
  for (int d = lane; d < DIM; d += 64) {
    sqc[w][d] = Uqc[rowo + d];
    skc[w][d] = Ukc[rowo + d];
    sw6[w][d] = W6g[rowo + d];
  }
  __syncthreads();
  {
    const int kk = lane & 31;
    const int h = lane >> 5;
    const int ik = sidx[w][kk];
    const float* qr = Uq + (size_t)(b * NP + ik) * DIM;
    const float* kr = Uk + (size_t)(b * NP + ik) * DIM;
    float lg = 0.f;
    const int d0 = h * (DIM / 2), d1 = d0 + DIM / 2;
    for (int d = d0; d < d1; d += 4) {
      float4 qa = *(const float4*)(qr + d);
      float4 ka = *(const float4*)(kr + d);
      float4 qc = *(const float4*)(&sqc[w][d]);
      float4 kc = *(const float4*)(&skc[w][d]);
      lg += (qa.x + qc.x) * (ka.x + kc.x);
      lg += (qa.y + qc.y) * (ka.y + kc.y);
      lg += (qa.z + qc.z) * (ka.z + kc.z);
      lg += (qa.w + qc.w) * (ka.w + kc.w);
    }
    lg += __shfl_xor(lg, 32);
    lg *= (DIM == 64) ? 0.125f : 0.08838834764831845f;  // 1/sqrt(DIM)
    float m = lg;
#pragma unroll
    for (int off = 16; off; off >>= 1) m = fmaxf(m, __shfl_xor(m, off));
    float e = expf(lg - m);
    float s = e;
#pragma unroll
    for (int off = 16; off; off >>= 1) s += __shfl_xor(s, off);
    if (lane < KNN) sattn[w][lane] = e / s;
  }
  __syncthreads();
  float acc[DIM / 64];
#pragma unroll
  for (int q = 0; q < DIM / 64; ++q) acc[q] = 0.f;
  for (int k = 0; k < KNN; ++k) {
    const int ik = sidx[w][k];
    const float a = sattn[w][k];
    const float* vr = Uv + (size_t)(b * NP + ik) * DIM;
#pragma unroll
    for (int q = 0; q < DIM / 64; ++q) {
      const int d = q * 64 + lane;
      acc[q] = fmaf(a, vr[d] + sw6[w][d], acc[q]);
    }
  }
#pragma unroll
  for (int q = 0; q < DIM / 64; ++q) outF[rowo + q * 64 + lane] = acc[q];
}

// ---------------------------------------------------------------------------
// Pooling: out[b][c] = max_n feats, out[b][256+c] = mean_n feats.
// ---------------------------------------------------------------------------
__global__ __launch_bounds__(256) void pool_kernel(const float* __restrict__ x1,
                                                   const float* __restrict__ x2,
                                                   const float* __restrict__ x3,
                                                   float* __restrict__ out) {
  const int b = blockIdx.x, c = threadIdx.x;
  const float* src;
  int dim, cl;
  if (c < 64) {
    src = x1 + (size_t)b * NP * 64; dim = 64; cl = c;
  } else if (c < 128) {
    src = x2 + (size_t)b * NP * 64; dim = 64; cl = c - 64;
  } else {
    src = x3 + (size_t)b * NP * 128; dim = 128; cl = c - 128;
  }
  float mx = NEG_INF, sm = 0.f;
#pragma unroll 8
  for (int n = 0; n < NP; ++n) {
    float v = src[(size_t)n * dim + cl];
    mx = fmaxf(mx, v);
    sm += v;
  }
  out[b * 512 + c] = mx;
  out[b * 512 + 256 + c] = sm * (1.0f / 2048.0f);
}

// ---------------------------------------------------------------------------
extern "C" void kernel_launch(void* const* d_in, const int* in_sizes, int n_in,
                              void* d_out, int out_size, void* d_ws, size_t ws_size,
                              hipStream_t stream) {
  const float* x = (const float*)d_in[0];
  const float* W[24];
  for (int i = 0; i < 24; ++i) W[i] = (const float*)d_in[1 + i];

  float* ws = (float*)d_ws;
  size_t off = 0;
  float* partial = ws + off; off += (size_t)NB * NP * 3;
  float* xxbuf = ws + off;   off += TOTPTS;
  int* idxb = (int*)(ws + off); off += (size_t)TOTPTS * KNN;
  float* x1 = ws + off; off += (size_t)TOTPTS * 64;
  float* x2 = ws + off; off += (size_t)TOTPTS * 64;
  float* x3 = ws + off; off += (size_t)TOTPTS * 128;
  float* Uq = ws + off;  off += (size_t)TOTPTS * 128;
  float* Uk = ws + off;  off += (size_t)TOTPTS * 128;
  float* Uv = ws + off;  off += (size_t)TOTPTS * 128;
  float* Uqc = ws + off; off += (size_t)TOTPTS * 128;
  float* Ukc = ws + off; off += (size_t)TOTPTS * 128;
  float* W6 = ws + off;  off += (size_t)TOTPTS * 128;
  float* Pbuf = ws + off; off += (size_t)TOTPTS * 128;
  float* Wcat = ws + off; off += (size_t)64 * 768;
  float* bcat = ws + off; off += 768;
  if (ws_size < off * sizeof(float)) return;

  float* Dbig = ws + off;
  const size_t need_big = (off + (size_t)NB * NP * NP) * sizeof(float);
  const bool bigws = (ws_size >= need_big);
  float* D = bigws ? Dbig : Uq;  // fallback: D aliases Uq..Uk region (16 MB)
  const int NZ = bigws ? NB : 1;

  fps_kernel<<<NB, 1024, 0, stream>>>(x, partial);

  // -------- layer 1 (C=3, DIM=64)
  xx_kernel<<<TOTPTS / 256, 256, 0, stream>>>(partial, xxbuf, 3);
  for (int b = 0; b < NB; b += NZ) {
    dist_gemm<3><<<dim3(32, 32, NZ), 256, 0, stream>>>(partial, xxbuf, D, b);
    select_kernel<<<dim3(NP / 4, 1, NZ), 256, 0, stream>>>(D, idxb, b);
  }
  proj_kernel<3, 64><<<TOTPTS / 16, 256, 0, stream>>>(
      partial, partial, W[0], W[1], W[2], W[3], W[4], W[5], W[6], W[7],
      Uq, Uk, Uv, Uqc, Ukc, W6);
  attn_kernel<64><<<TOTPTS / 4, 256, 0, stream>>>(Uq, Uk, Uv, Uqc, Ukc, W6, idxb, x1);

  // -------- layer 2 (C=64, DIM=64)
  xx_kernel<<<TOTPTS / 256, 256, 0, stream>>>(x1, xxbuf, 64);
  for (int b = 0; b < NB; b += NZ) {
    dist_gemm<64><<<dim3(32, 32, NZ), 256, 0, stream>>>(x1, xxbuf, D, b);
    select_kernel<<<dim3(NP / 4, 1, NZ), 256, 0, stream>>>(D, idxb, b);
  }
  prep_kernel<64><<<2, 256, 0, stream>>>(W[8], W[9], W[10], W[11], W[12], W[13], Wcat, bcat);
  pos_kernel<64><<<TOTPTS * 64 / 256, 256, 0, stream>>>(partial, W[14], W[15], Pbuf);
  gemm_proj<64><<<dim3(TOTPTS / 64, 6), 256, 0, stream>>>(
      x1, Wcat, bcat, Pbuf, Uq, Uqc, Uk, Ukc, Uv, W6);
  attn_kernel<64><<<TOTPTS / 4, 256, 0, stream>>>(Uq, Uk, Uv, Uqc, Ukc, W6, idxb, x2);

  // -------- layer 3 (C=64, DIM=128)
  xx_kernel<<<TOTPTS / 256, 256, 0, stream>>>(x2, xxbuf, 64);
  for (int b = 0; b < NB; b += NZ) {
    dist_gemm<64><<<dim3(32, 32, NZ), 256, 0, stream>>>(x2, xxbuf, D, b);
    select_kernel<<<dim3(NP / 4, 1, NZ), 256, 0, stream>>>(D, idxb, b);
  }
  prep_kernel<128><<<3, 256, 0, stream>>>(W[16], W[17], W[18], W[19], W[20], W[21], Wcat, bcat);
  pos_kernel<128><<<TOTPTS * 128 / 256, 256, 0, stream>>>(partial, W[22], W[23], Pbuf);
  gemm_proj<128><<<dim3(TOTPTS / 64, 12), 256, 0, stream>>>(
      x2, Wcat, bcat, Pbuf, Uq, Uqc, Uk, Ukc, Uv, W6);
  attn_kernel<128><<<TOTPTS / 4, 256, 0, stream>>>(Uq, Uk, Uv, Uqc, Ukc, W6, idxb, x3);

  pool_kernel<<<NB, 256, 0, stream>>>(x1, x2, x3, (float*)d_out);
}